// Round 1
// 80.507 us; speedup vs baseline: 1.1229x; 1.1229x over previous
//
#include <hip/hip_runtime.h>

// AffinityLoss: logits (2,19,384,384) fp32, labels (2,384,384) int32 -> scalar fp32.
// R3: (a) LDS channel stride padded 19->20 floats (80B, 16B-aligned) so each
//     19-dot is 5x ds_read_b128 (conflict-free: lane stride 20 floats covers
//     all 32 banks per 8 lanes) instead of 19x ds_read_b32;
//     (b) bce(x,y) = softplus((1-2y)x) computed with hw v_exp_f32/v_log_f32
//     (2 trans + ~5 VALU) replacing libm log1pf+expf (~35 instrs);
//     (c) multiplicities precomputed (8 values), TY=12 -> 768 blocks = 3/CU.

#define IGNORE_INDEX (-100)

constexpr int Hh = 384, Ww = 384, Cc = 19;
constexpr int HW = Hh * Ww;                  // 147456
constexpr int HP = 382, WP = 382;            // h-k+1, w-k+1
constexpr int TX = 32, TY = 12;              // pixel tile per block
constexpr int NT = TX * TY;                  // 384 threads = 6 waves
constexpr int LXX = TX + 4;                  // halo: dx in [-2,2] -> 36
constexpr int LYY = TY + 2;                  // halo: dy in [0,2]  -> 14
constexpr int CS  = 20;                      // padded channel stride (floats)
constexpr int NBX = Ww / TX, NBY = Hh / TY;  // 12, 32
constexpr int NBLK = NBX * NBY * 2;          // 768

// multiplicity of (pixel row y, row-offset di>=0)
__device__ __forceinline__ int mult_y(int y, int di) {
    int lo = y - (HP - 1); if (lo < 0) lo = 0;
    int hi = 2 - di;       if (y < hi) hi = y;
    int c = hi - lo + 1;   return c > 0 ? c : 0;
}
// multiplicity of (pixel col x, col-offset dj in [-2,2])
__device__ __forceinline__ int mult_x(int x, int dj) {
    int lo = (-dj > 0) ? -dj : 0;
    int lo2 = x - (WP - 1); if (lo2 > lo) lo = lo2;
    int hi = (2 - dj < 2) ? (2 - dj) : 2;
    if (x < hi) hi = x;
    int c = hi - lo + 1;   return c > 0 ? c : 0;
}

// softplus(t) = log(1+exp(t)) = max(t,0) + ln2*log2(1 + 2^(-|t|*log2e))
// == max(x,0) - x*y + log1p(exp(-|x|)) with t = (1-2y)*x, y in {0,1}
__device__ __forceinline__ float softplus(float t) {
    float e = __builtin_amdgcn_exp2f(-1.4426950408889634f * fabsf(t));
    float l = __builtin_amdgcn_logf(1.0f + e);
    return fmaxf(t, 0.0f) + 0.6931471805599453f * l;
}

__global__ __launch_bounds__(NT) void aff_loss_kernel(
        const float* __restrict__ logits, const int* __restrict__ labels,
        double* __restrict__ partial) {
    __shared__ __align__(16) float sv[LYY * LXX * CS];  // [entry][c], stride 20
    __shared__ int    sl[LYY * LXX];
    __shared__ double sred[NT / 64];

    const int n   = blockIdx.z;
    const int tx0 = blockIdx.x * TX;
    const int ty0 = blockIdx.y * TY;
    const int tid = threadIdx.x;
    const int bid = (blockIdx.z * NBY + blockIdx.y) * NBX + blockIdx.x;

    const float* img = logits + (size_t)n * Cc * HW;
    const int*   lab = labels + (size_t)n * HW;

    // stage tile + halo (clamped at borders; clamped pixels only ever used
    // with multiplicity 0). 5x ds_write_b128 per entry, pad elem zeroed.
    for (int idx = tid; idx < LYY * LXX; idx += NT) {
        int r = idx / LXX, col = idx - r * LXX;
        int gy = ty0 + r;       if (gy > Hh - 1) gy = Hh - 1;
        int gx = tx0 + col - 2; if (gx < 0) gx = 0; if (gx > Ww - 1) gx = Ww - 1;
        sl[idx] = lab[gy * Ww + gx];
        const float* s = img + gy * Ww + gx;
        float4 t0, t1, t2, t3, t4;
        t0.x = s[0 * HW];  t0.y = s[1 * HW];  t0.z = s[2 * HW];  t0.w = s[3 * HW];
        t1.x = s[4 * HW];  t1.y = s[5 * HW];  t1.z = s[6 * HW];  t1.w = s[7 * HW];
        t2.x = s[8 * HW];  t2.y = s[9 * HW];  t2.z = s[10 * HW]; t2.w = s[11 * HW];
        t3.x = s[12 * HW]; t3.y = s[13 * HW]; t3.z = s[14 * HW]; t3.w = s[15 * HW];
        t4.x = s[16 * HW]; t4.y = s[17 * HW]; t4.z = s[18 * HW]; t4.w = 0.0f;
        float4* dst = reinterpret_cast<float4*>(&sv[idx * CS]);
        dst[0] = t0; dst[1] = t1; dst[2] = t2; dst[3] = t3; dst[4] = t4;
    }
    __syncthreads();

    const int tx = tid & (TX - 1), ty = tid >> 5;   // TX == 32
    const int x = tx0 + tx, y = ty0 + ty;
    const int ep = ty * LXX + (tx + 2);

    const float4* P = reinterpret_cast<const float4*>(&sv[ep * CS]);
    const float4 p0 = P[0], p1 = P[1], p2 = P[2], p3 = P[3], p4 = P[4];
    const int lp = sl[ep];
    const bool vp = (lp != IGNORE_INDEX);

    // precompute multiplicities: rows dy in {0,1,2}, cols dj in {-2..2}
    int my_[3], mx_[5];
    my_[0] = mult_y(y, 0); my_[1] = mult_y(y, 1); my_[2] = mult_y(y, 2);
    #pragma unroll
    for (int j = 0; j < 5; ++j) mx_[j] = mult_x(x, j - 2);

    double tsum = 0.0;

    // d=0 is the diagonal (weight w); d>=1 are the 12 lexicographically
    // positive offsets, each counted twice ((a,b),(b,a)) -> weight 2w.
    const int DY[13] = {0, 0, 0, 1, 1, 1, 1, 1, 2, 2, 2, 2, 2};
    const int DX[13] = {0, 1, 2, -2, -1, 0, 1, 2, -2, -1, 0, 1, 2};
    #pragma unroll
    for (int d = 0; d < 13; ++d) {
        const int dy = DY[d], dx = DX[d];
        float4 b0, b1, b2, b3, b4; int lq;
        if (d == 0) {
            b0 = p0; b1 = p1; b2 = p2; b3 = p3; b4 = p4; lq = lp;
        } else {
            const int eq = (ty + dy) * LXX + (tx + 2 + dx);
            const float4* Q = reinterpret_cast<const float4*>(&sv[eq * CS]);
            b0 = Q[0]; b1 = Q[1]; b2 = Q[2]; b3 = Q[3]; b4 = Q[4];
            lq = sl[eq];
        }
        // 19-term dot, two chains for latency
        float xa = p0.x * b0.x, xb = p0.y * b0.y;
        xa = fmaf(p0.z, b0.z, xa); xb = fmaf(p0.w, b0.w, xb);
        xa = fmaf(p1.x, b1.x, xa); xb = fmaf(p1.y, b1.y, xb);
        xa = fmaf(p1.z, b1.z, xa); xb = fmaf(p1.w, b1.w, xb);
        xa = fmaf(p2.x, b2.x, xa); xb = fmaf(p2.y, b2.y, xb);
        xa = fmaf(p2.z, b2.z, xa); xb = fmaf(p2.w, b2.w, xb);
        xa = fmaf(p3.x, b3.x, xa); xb = fmaf(p3.y, b3.y, xb);
        xa = fmaf(p3.z, b3.z, xa); xb = fmaf(p3.w, b3.w, xb);
        xa = fmaf(p4.x, b4.x, xa); xb = fmaf(p4.y, b4.y, xb);
        xa = fmaf(p4.z, b4.z, xa);
        const float xd = xa + xb;

        const bool same = vp && (lq == lp);          // y in {0,1}
        const float t = same ? -xd : xd;             // (1-2y)*x
        const float f = softplus(t);
        const int w = my_[dy] * mx_[dx + 2] * (d == 0 ? 1 : 2);
        tsum += (double)((float)w * f);
    }

    // reduce: wave shuffle -> LDS -> one plain store per block (distinct slot)
    for (int off = 32; off > 0; off >>= 1) tsum += __shfl_down(tsum, off, 64);
    const int wid = tid >> 6;
    if ((tid & 63) == 0) sred[wid] = tsum;
    __syncthreads();
    if (tid == 0) {
        double s = 0.0;
        #pragma unroll
        for (int i = 0; i < NT / 64; ++i) s += sred[i];
        partial[bid] = s;
    }
}

__global__ __launch_bounds__(256) void finalize_kernel(
        const double* __restrict__ partial, float* __restrict__ out) {
    __shared__ double sred[4];
    const int tid = threadIdx.x;
    double s = 0.0;
    for (int i = tid; i < NBLK; i += 256) s += partial[i];
    for (int off = 32; off > 0; off >>= 1) s += __shfl_down(s, off, 64);
    if ((tid & 63) == 0) sred[tid >> 6] = s;
    __syncthreads();
    if (tid == 0) {
        // mean over n*9*9*L = 2*81*382*382 = 23,639,688 terms
        double tot = sred[0] + sred[1] + sred[2] + sred[3];
        out[0] = (float)(tot * (1.0 / 23639688.0));
    }
}

extern "C" void kernel_launch(void* const* d_in, const int* in_sizes, int n_in,
                              void* d_out, int out_size, void* d_ws, size_t ws_size,
                              hipStream_t stream) {
    const float* logits = (const float*)d_in[0];
    const int*   labels = (const int*)d_in[1];
    float* out = (float*)d_out;
    double* partial = (double*)d_ws;   // NBLK doubles, written unconditionally

    dim3 grid(NBX, NBY, 2);   // 12 x 32 x 2 = 768 blocks
    aff_loss_kernel<<<grid, NT, 0, stream>>>(logits, labels, partial);
    finalize_kernel<<<1, 256, 0, stream>>>(partial, out);
}

// Round 2
// 80.381 us; speedup vs baseline: 1.1247x; 1.0016x over previous
//
#include <hip/hip_runtime.h>

// AffinityLoss: logits (2,19,384,384) fp32, labels (2,384,384) int32 -> scalar fp32.
// R4: latency-bound fix. R3 (TY=12, 6-wave blocks) capped at 2 blocks/CU = 12
// waves (VGPR in (64,128] -> 16 wave slots; 6-wave blocks don't pack).
// (a) TY=8, 256-thr blocks + __launch_bounds__(256,4): 4 blocks x 4 waves
//     = 16 waves/CU resident;
// (b) neighbors processed in PAIRS: 2 independent 19-dots (2 chains each)
//     in flight -> 4 live FMA chains to hide ds_read/FMA latency;
// (c) f32 accumulation + f32 wave reduce (double only once per block);
// (d) float multiplicity weights.

#define IGNORE_INDEX (-100)

constexpr int Hh = 384, Ww = 384, Cc = 19;
constexpr int HW = Hh * Ww;                  // 147456
constexpr int HP = 382, WP = 382;            // h-k+1, w-k+1
constexpr int TX = 32, TY = 8;               // pixel tile per block
constexpr int NT = TX * TY;                  // 256 threads = 4 waves
constexpr int LXX = TX + 4;                  // halo: dx in [-2,2] -> 36
constexpr int LYY = TY + 2;                  // halo: dy in [0,2]  -> 10
constexpr int CS  = 20;                      // padded channel stride (floats)
constexpr int NBX = Ww / TX, NBY = Hh / TY;  // 12, 48
constexpr int NBLK = NBX * NBY * 2;          // 1152

__device__ __forceinline__ int mult_y(int y, int di) {
    int lo = y - (HP - 1); if (lo < 0) lo = 0;
    int hi = 2 - di;       if (y < hi) hi = y;
    int c = hi - lo + 1;   return c > 0 ? c : 0;
}
__device__ __forceinline__ int mult_x(int x, int dj) {
    int lo = (-dj > 0) ? -dj : 0;
    int lo2 = x - (WP - 1); if (lo2 > lo) lo = lo2;
    int hi = (2 - dj < 2) ? (2 - dj) : 2;
    if (x < hi) hi = x;
    int c = hi - lo + 1;   return c > 0 ? c : 0;
}

// softplus(t) = max(t,0) + ln2*log2(1 + 2^(-|t|*log2e))
__device__ __forceinline__ float softplus(float t) {
    float e = __builtin_amdgcn_exp2f(-1.4426950408889634f * fabsf(t));
    float l = __builtin_amdgcn_logf(1.0f + e);
    return fmaxf(t, 0.0f) + 0.6931471805599453f * l;
}

__global__ __launch_bounds__(NT, 4) void aff_loss_kernel(
        const float* __restrict__ logits, const int* __restrict__ labels,
        double* __restrict__ partial) {
    __shared__ __align__(16) float sv[LYY * LXX * CS];  // [entry][c], stride 20
    __shared__ int   sl[LYY * LXX];
    __shared__ float sred[NT / 64];

    const int n   = blockIdx.z;
    const int tx0 = blockIdx.x * TX;
    const int ty0 = blockIdx.y * TY;
    const int tid = threadIdx.x;
    const int bid = (blockIdx.z * NBY + blockIdx.y) * NBX + blockIdx.x;

    const float* img = logits + (size_t)n * Cc * HW;
    const int*   lab = labels + (size_t)n * HW;

    // stage tile + halo (border-clamped entries only used with multiplicity 0)
    for (int idx = tid; idx < LYY * LXX; idx += NT) {
        int r = idx / LXX, col = idx - r * LXX;
        int gy = ty0 + r;       if (gy > Hh - 1) gy = Hh - 1;
        int gx = tx0 + col - 2; if (gx < 0) gx = 0; if (gx > Ww - 1) gx = Ww - 1;
        sl[idx] = lab[gy * Ww + gx];
        const float* s = img + gy * Ww + gx;
        float4 t0, t1, t2, t3, t4;
        t0.x = s[0 * HW];  t0.y = s[1 * HW];  t0.z = s[2 * HW];  t0.w = s[3 * HW];
        t1.x = s[4 * HW];  t1.y = s[5 * HW];  t1.z = s[6 * HW];  t1.w = s[7 * HW];
        t2.x = s[8 * HW];  t2.y = s[9 * HW];  t2.z = s[10 * HW]; t2.w = s[11 * HW];
        t3.x = s[12 * HW]; t3.y = s[13 * HW]; t3.z = s[14 * HW]; t3.w = s[15 * HW];
        t4.x = s[16 * HW]; t4.y = s[17 * HW]; t4.z = s[18 * HW]; t4.w = 0.0f;
        float4* dst = reinterpret_cast<float4*>(&sv[idx * CS]);
        dst[0] = t0; dst[1] = t1; dst[2] = t2; dst[3] = t3; dst[4] = t4;
    }
    __syncthreads();

    const int tx = tid & (TX - 1), ty = tid >> 5;   // TX == 32
    const int x = tx0 + tx, y = ty0 + ty;
    const int ep = ty * LXX + (tx + 2);

    const float4* P = reinterpret_cast<const float4*>(&sv[ep * CS]);
    const float4 p0 = P[0], p1 = P[1], p2 = P[2], p3 = P[3], p4 = P[4];
    const int lp = sl[ep];
    const bool vp = (lp != IGNORE_INDEX);

    // float multiplicity weights: rows dy in {0,1,2}, cols dj in {-2..2}
    float myf[3], mxf[5];
    #pragma unroll
    for (int i = 0; i < 3; ++i) myf[i] = (float)mult_y(y, i);
    #pragma unroll
    for (int j = 0; j < 5; ++j) mxf[j] = (float)mult_x(x, j - 2);

    // 19-term dot against p-regs, two chains
    auto dot19 = [&](float4 b0, float4 b1, float4 b2, float4 b3, float4 b4) {
        float xa = p0.x * b0.x, xb = p0.y * b0.y;
        xa = fmaf(p0.z, b0.z, xa); xb = fmaf(p0.w, b0.w, xb);
        xa = fmaf(p1.x, b1.x, xa); xb = fmaf(p1.y, b1.y, xb);
        xa = fmaf(p1.z, b1.z, xa); xb = fmaf(p1.w, b1.w, xb);
        xa = fmaf(p2.x, b2.x, xa); xb = fmaf(p2.y, b2.y, xb);
        xa = fmaf(p2.z, b2.z, xa); xb = fmaf(p2.w, b2.w, xb);
        xa = fmaf(p3.x, b3.x, xa); xb = fmaf(p3.y, b3.y, xb);
        xa = fmaf(p3.z, b3.z, xa); xb = fmaf(p3.w, b3.w, xb);
        xa = fmaf(p4.x, b4.x, xa); xb = fmaf(p4.y, b4.y, xb);
        xa = fmaf(p4.z, b4.z, xa);
        return xa + xb;
    };

    float tsum;
    // diagonal (b == p, weight w): y=1 iff valid; softplus form is uniform
    {
        float xd = dot19(p0, p1, p2, p3, p4);
        float t = vp ? -xd : xd;
        tsum = (myf[0] * mxf[2]) * softplus(t);
    }

    // 12 lexicographically-positive offsets, processed in pairs for ILP;
    // each counted twice ((a,b),(b,a)) -> weight 2w.
    const int DY[12] = {0, 0, 1, 1, 1, 1, 1, 2, 2, 2, 2, 2};
    const int DX[12] = {1, 2, -2, -1, 0, 1, 2, -2, -1, 0, 1, 2};
    #pragma unroll
    for (int dd = 0; dd < 12; dd += 2) {
        const int dy0 = DY[dd], dx0 = DX[dd];
        const int dy1 = DY[dd + 1], dx1 = DX[dd + 1];
        const int eq0 = (ty + dy0) * LXX + (tx + 2 + dx0);
        const int eq1 = (ty + dy1) * LXX + (tx + 2 + dx1);
        const float4* Q0 = reinterpret_cast<const float4*>(&sv[eq0 * CS]);
        const float4* Q1 = reinterpret_cast<const float4*>(&sv[eq1 * CS]);
        float4 a0 = Q0[0], a1 = Q0[1], a2 = Q0[2], a3 = Q0[3], a4 = Q0[4];
        float4 c0 = Q1[0], c1 = Q1[1], c2 = Q1[2], c3 = Q1[3], c4 = Q1[4];
        const int lq0 = sl[eq0], lq1 = sl[eq1];
        const float x0 = dot19(a0, a1, a2, a3, a4);
        const float x1 = dot19(c0, c1, c2, c3, c4);
        const float t0 = (vp && lq0 == lp) ? -x0 : x0;
        const float t1 = (vp && lq1 == lp) ? -x1 : x1;
        const float w0 = 2.0f * myf[dy0] * mxf[dx0 + 2];
        const float w1 = 2.0f * myf[dy1] * mxf[dx1 + 2];
        tsum = fmaf(w0, softplus(t0), tsum);
        tsum = fmaf(w1, softplus(t1), tsum);
    }

    // reduce: f32 wave shuffle -> LDS -> one double store per block
    for (int off = 32; off > 0; off >>= 1) tsum += __shfl_down(tsum, off, 64);
    const int wid = tid >> 6;
    if ((tid & 63) == 0) sred[wid] = tsum;
    __syncthreads();
    if (tid == 0) {
        double s = 0.0;
        #pragma unroll
        for (int i = 0; i < NT / 64; ++i) s += (double)sred[i];
        partial[bid] = s;
    }
}

__global__ __launch_bounds__(256) void finalize_kernel(
        const double* __restrict__ partial, float* __restrict__ out) {
    __shared__ double sred[4];
    const int tid = threadIdx.x;
    double s = 0.0;
    for (int i = tid; i < NBLK; i += 256) s += partial[i];
    for (int off = 32; off > 0; off >>= 1) s += __shfl_down(s, off, 64);
    if ((tid & 63) == 0) sred[tid >> 6] = s;
    __syncthreads();
    if (tid == 0) {
        // mean over n*9*9*L = 2*81*382*382 = 23,639,688 terms
        double tot = sred[0] + sred[1] + sred[2] + sred[3];
        out[0] = (float)(tot * (1.0 / 23639688.0));
    }
}

extern "C" void kernel_launch(void* const* d_in, const int* in_sizes, int n_in,
                              void* d_out, int out_size, void* d_ws, size_t ws_size,
                              hipStream_t stream) {
    const float* logits = (const float*)d_in[0];
    const int*   labels = (const int*)d_in[1];
    float* out = (float*)d_out;
    double* partial = (double*)d_ws;   // NBLK doubles, written unconditionally

    dim3 grid(NBX, NBY, 2);   // 12 x 48 x 2 = 1152 blocks
    aff_loss_kernel<<<grid, NT, 0, stream>>>(logits, labels, partial);
    finalize_kernel<<<1, 256, 0, stream>>>(partial, out);
}